// Round 1
// baseline (2140.982 us; speedup 1.0000x reference)
//
#include <hip/hip_runtime.h>
#include <math.h>

// EdgeConditionedConv on MI355X — round 0: correct fp32 baseline.
// messages fused as tiled GEMM (U = H @ W2^T per 64-col slice) + contraction
// with gathered x[src] + atomic scatter into agg[dst], then GRU cell.

constexpr int N_NODES  = 25000;
constexpr int N_EDGES  = 50000;
constexpr int NODE_DIM = 64;
constexpr int EDGE_DIM = 16;
constexpr int HID      = 128;
constexpr int BE       = 32;   // edges per block in message kernel

// ---------------------------------------------------------------- phase 1
// h[e,k] = gelu_exact(edge_attr[e,:] . W1[k,:] + b1[k]),  h: [E][128]
__global__ __launch_bounds__(256) void edge_mlp1_kernel(
    const float* __restrict__ edge_attr,
    const float* __restrict__ W1,
    const float* __restrict__ b1,
    float* __restrict__ h)
{
    int e = blockIdx.x * 2 + (threadIdx.x >> 7);
    int k = threadIdx.x & 127;
    if (e >= N_EDGES) return;
    const float* ea = edge_attr + (size_t)e * EDGE_DIM;
    const float* w  = W1 + (size_t)k * EDGE_DIM;
    float acc = b1[k];
#pragma unroll
    for (int d = 0; d < EDGE_DIM; ++d) acc += ea[d] * w[d];
    // exact gelu: x * 0.5 * (1 + erf(x/sqrt(2)))
    float g = 0.5f * acc * (1.0f + erff(acc * 0.70710678118654752f));
    h[(size_t)e * HID + k] = g;
}

// ---------------------------------------------------------------- phase 2
// For block (i, eb): U[e, j] = H[e,:] . W2[i*64+j, :] + b2[i*64+j]
// msg[e, i] = sum_j U[e,j] * x[src[e], j];  atomicAdd(agg[dst[e], i], msg)
// LDS tiles XOR-swizzled at float4 granularity: phys = idx ^ ((row>>2)&7)
__global__ __launch_bounds__(128) void edge_msg_kernel(
    const float* __restrict__ h,
    const float* __restrict__ x,
    const int*   __restrict__ edge_index,   // [2][E] (src row 0, dst row 1)
    const float* __restrict__ W2,           // [4096][128]
    const float* __restrict__ b2,           // [4096]
    float* __restrict__ agg)                // [N][64], pre-zeroed
{
    __shared__ float4 W2s4[64 * 32];        // 32 KB: rows i*64..i*64+63 of W2
    __shared__ float4 Hs4[BE * 32];         // 16 KB
    __shared__ float  xsh[BE][NODE_DIM];    // 8 KB
    __shared__ float  b2s[64];
    __shared__ int    dsts[BE];

    const int i  = blockIdx.x;              // output row 0..63
    const int e0 = blockIdx.y * BE;
    const int t  = threadIdx.x;             // 0..127

    // stage W2 slice (8192 floats contiguous), swizzled
    const float4* w2src = reinterpret_cast<const float4*>(W2 + (size_t)i * 64 * HID);
#pragma unroll
    for (int r = 0; r < 16; ++r) {
        int idx = t + r * 128;                       // row = idx>>5, k4 = idx&31
        W2s4[idx ^ ((idx >> 7) & 7)] = w2src[idx];
    }
    if (t < 64) b2s[t] = b2[(size_t)i * 64 + t];

    // stage H block (rows e0..e0+31), zero-fill tail, swizzled
    const float4* hsrc = reinterpret_cast<const float4*>(h + (size_t)e0 * HID);
    int nval4 = min(N_EDGES - e0, BE) * (HID / 4);
#pragma unroll
    for (int r = 0; r < 8; ++r) {
        int idx = t + r * 128;
        float4 v = make_float4(0.f, 0.f, 0.f, 0.f);
        if (idx < nval4) v = hsrc[idx];
        Hs4[idx ^ ((idx >> 7) & 7)] = v;
    }

    // gather x[src[e]] : 4 threads per edge, 4 float4 each
    {
        int le = t >> 2, sub = t & 3;
        int e = e0 + le;
        float4* xd = reinterpret_cast<float4*>(&xsh[le][0]);
        if (e < N_EDGES) {
            int s = edge_index[e];
            if (sub == 0) dsts[le] = edge_index[N_EDGES + e];
            if ((unsigned)s < (unsigned)N_NODES) {
                const float4* xsrc = reinterpret_cast<const float4*>(x + (size_t)s * NODE_DIM);
#pragma unroll
                for (int r2 = 0; r2 < 4; ++r2) xd[sub + 4 * r2] = xsrc[sub + 4 * r2];
            } else {
#pragma unroll
                for (int r2 = 0; r2 < 4; ++r2) xd[sub + 4 * r2] = make_float4(0.f, 0.f, 0.f, 0.f);
            }
        } else {
            if (sub == 0) dsts[le] = -1;
#pragma unroll
            for (int r2 = 0; r2 < 4; ++r2) xd[sub + 4 * r2] = make_float4(0.f, 0.f, 0.f, 0.f);
        }
    }
    __syncthreads();

    // 4 edges x 4 j per thread: jg = t&15 -> j0 = 4*jg ; eg = t>>4 -> es = 4*eg
    const int jg = t & 15, eg = t >> 4;
    const int j0 = jg * 4, es = eg * 4;

    float acc[4][4] = {};
#pragma unroll 4
    for (int k4 = 0; k4 < 32; ++k4) {
        const int kw = k4 ^ (jg & 7);   // physical slot of logical k4 in W2 rows
        const int kh = k4 ^ eg;         // physical slot of logical k4 in H rows
        float4 w[4], hv[4];
#pragma unroll
        for (int b = 0; b < 4; ++b) w[b] = W2s4[((j0 + b) << 5) | kw];
#pragma unroll
        for (int a = 0; a < 4; ++a) hv[a] = Hs4[((es + a) << 5) | kh];
#pragma unroll
        for (int a = 0; a < 4; ++a)
#pragma unroll
            for (int b = 0; b < 4; ++b)
                acc[a][b] += hv[a].x * w[b].x + hv[a].y * w[b].y
                           + hv[a].z * w[b].z + hv[a].w * w[b].w;
    }

    // epilogue: u = acc + b2; contract with xs over j; reduce over 16 jg-lanes
    float msum[4];
#pragma unroll
    for (int a = 0; a < 4; ++a) {
        float s = 0.f;
#pragma unroll
        for (int b = 0; b < 4; ++b) {
            float u = acc[a][b] + b2s[j0 + b];
            s += u * xsh[es + a][j0 + b];
        }
        msum[a] = s;
    }
#pragma unroll
    for (int m = 1; m < 16; m <<= 1) {
#pragma unroll
        for (int a = 0; a < 4; ++a) msum[a] += __shfl_xor(msum[a], m);
    }
    if (jg == 0) {
#pragma unroll
        for (int a = 0; a < 4; ++a) {
            int d = dsts[es + a];
            if ((unsigned)d < (unsigned)N_NODES)
                atomicAdd(&agg[(size_t)d * NODE_DIM + i], msum[a]);
        }
    }
}

// ---------------------------------------------------------------- phase 3
// GRUCell: one wave per node; lane t owns output dim t (6 length-64 dots)
__global__ __launch_bounds__(64) void gru_kernel(
    const float* __restrict__ agg,
    const float* __restrict__ x,
    const float* __restrict__ w_ih,
    const float* __restrict__ w_hh,
    const float* __restrict__ b_ih,
    const float* __restrict__ b_hh,
    float* __restrict__ out)
{
    int n = blockIdx.x;
    int t = threadIdx.x;
    __shared__ float as_[NODE_DIM], xs_[NODE_DIM];
    as_[t] = agg[(size_t)n * NODE_DIM + t];
    xs_[t] = x[(size_t)n * NODE_DIM + t];
    __syncthreads();

    float ir = b_ih[t], iz = b_ih[64 + t], inn = b_ih[128 + t];
    float hr = b_hh[t], hz = b_hh[64 + t], hn  = b_hh[128 + t];
    const float4* wi0 = reinterpret_cast<const float4*>(w_ih + (size_t)(t)       * 64);
    const float4* wi1 = reinterpret_cast<const float4*>(w_ih + (size_t)(64 + t)  * 64);
    const float4* wi2 = reinterpret_cast<const float4*>(w_ih + (size_t)(128 + t) * 64);
    const float4* wh0 = reinterpret_cast<const float4*>(w_hh + (size_t)(t)       * 64);
    const float4* wh1 = reinterpret_cast<const float4*>(w_hh + (size_t)(64 + t)  * 64);
    const float4* wh2 = reinterpret_cast<const float4*>(w_hh + (size_t)(128 + t) * 64);

#pragma unroll
    for (int kq = 0; kq < 16; ++kq) {
        float4 a4 = *reinterpret_cast<const float4*>(&as_[kq * 4]);
        float4 x4 = *reinterpret_cast<const float4*>(&xs_[kq * 4]);
        float4 w;
        w = wi0[kq]; ir  += a4.x * w.x + a4.y * w.y + a4.z * w.z + a4.w * w.w;
        w = wi1[kq]; iz  += a4.x * w.x + a4.y * w.y + a4.z * w.z + a4.w * w.w;
        w = wi2[kq]; inn += a4.x * w.x + a4.y * w.y + a4.z * w.z + a4.w * w.w;
        w = wh0[kq]; hr  += x4.x * w.x + x4.y * w.y + x4.z * w.z + x4.w * w.w;
        w = wh1[kq]; hz  += x4.x * w.x + x4.y * w.y + x4.z * w.z + x4.w * w.w;
        w = wh2[kq]; hn  += x4.x * w.x + x4.y * w.y + x4.z * w.z + x4.w * w.w;
    }
    float r  = 1.f / (1.f + expf(-(ir + hr)));
    float z  = 1.f / (1.f + expf(-(iz + hz)));
    float nn = tanhf(inn + r * hn);
    out[(size_t)n * NODE_DIM + t] = (1.f - z) * nn + z * xs_[t];
}

// ---------------------------------------------------------------- launch
extern "C" void kernel_launch(void* const* d_in, const int* in_sizes, int n_in,
                              void* d_out, int out_size, void* d_ws, size_t ws_size,
                              hipStream_t stream)
{
    const float* x          = (const float*)d_in[0];
    const int*   edge_index = (const int*)  d_in[1];
    const float* edge_attr  = (const float*)d_in[2];
    const float* W1         = (const float*)d_in[3];
    const float* b1         = (const float*)d_in[4];
    const float* W2         = (const float*)d_in[5];
    const float* b2         = (const float*)d_in[6];
    const float* w_ih       = (const float*)d_in[7];
    const float* w_hh       = (const float*)d_in[8];
    const float* b_ih       = (const float*)d_in[9];
    const float* b_hh       = (const float*)d_in[10];
    float* out = (float*)d_out;

    float* hbuf = (float*)d_ws;                                            // E*128 f32 = 25.6 MB
    float* agg  = (float*)((char*)d_ws + (size_t)N_EDGES * HID * sizeof(float)); // N*64 f32 = 6.4 MB

    hipMemsetAsync(agg, 0, (size_t)N_NODES * NODE_DIM * sizeof(float), stream);

    edge_mlp1_kernel<<<dim3(N_EDGES / 2), dim3(256), 0, stream>>>(edge_attr, W1, b1, hbuf);

    edge_msg_kernel<<<dim3(64, (N_EDGES + BE - 1) / BE), dim3(128), 0, stream>>>(
        hbuf, x, edge_index, W2, b2, agg);

    gru_kernel<<<dim3(N_NODES), dim3(64), 0, stream>>>(agg, x, w_ih, w_hh, b_ih, b_hh, out);
}

// Round 2
// 885.810 us; speedup vs baseline: 2.4170x; 2.4170x over previous
//
#include <hip/hip_runtime.h>
#include <math.h>

// EdgeConditionedConv on MI355X — round 1: MFMA (f16) rank-1-factored messages.
// messages[e,i] = sum_j g[e,j] * P_j[i,e],  P_j = W2_j(f16) @ h(f16)^T  via
// mfma_f32_16x16x32_f16; g applied as per-lane scalar VALU epilogue per j.
// Bias: wave-0 MFMA with prepacked b2 fragments. Scatter via f32 atomics.

constexpr int N_NODES  = 25000;
constexpr int N_EDGES  = 50000;
constexpr int NODE_DIM = 64;
constexpr int EDGE_DIM = 16;
constexpr int HID      = 128;

typedef __attribute__((ext_vector_type(8))) _Float16 half8;
typedef __attribute__((ext_vector_type(4))) float    f32x4;

// ---------------------------------------------------------------- prepack
// Wpk chunk c = ((j*4+ks)*4+mt)*64+lane : 8 f16 = W2[(mt*16+(lane&15))*64+j][ks*32+((lane>>4)&3)*8 + 0..7]
// b2pk chunk c2 = (ks2*4+mt)*64+lane    : 8 f16 = b2[(mt*16+(lane&15))*64 + ks2*32+((lane>>4)&3)*8 + 0..7]
__global__ __launch_bounds__(256) void prepack_kernel(
    const float* __restrict__ W2, const float* __restrict__ b2,
    _Float16* __restrict__ Wpk, _Float16* __restrict__ b2pk)
{
    int c = blockIdx.x * 256 + threadIdx.x;
    if (c < 65536) {
        int lane = c & 63, mt = (c >> 6) & 3, ks = (c >> 8) & 3, j = c >> 10;
        int i   = mt * 16 + (lane & 15);
        int col = ks * 32 + ((lane >> 4) & 3) * 8;
        const float* src = W2 + (size_t)(i * 64 + j) * HID + col;
        half8 o;
#pragma unroll
        for (int q = 0; q < 8; ++q) o[q] = (_Float16)src[q];
        ((half8*)Wpk)[c] = o;
    } else if (c < 65536 + 512) {
        int c2 = c - 65536;
        int lane = c2 & 63, mt = (c2 >> 6) & 3, ks2 = (c2 >> 8) & 1;
        int i = mt * 16 + (lane & 15);
        int j = ks2 * 32 + ((lane >> 4) & 3) * 8;
        const float* src = b2 + i * 64 + j;
        half8 o;
#pragma unroll
        for (int q = 0; q < 8; ++q) o[q] = (_Float16)src[q];
        ((half8*)b2pk)[c2] = o;
    }
}

// ---------------------------------------------------------------- phase 1
// h[e,k] = gelu_exact(edge_attr[e,:] . W1[k,:] + b1[k]) -> f16
__global__ __launch_bounds__(256) void edge_mlp1_kernel(
    const float* __restrict__ edge_attr,
    const float* __restrict__ W1,
    const float* __restrict__ b1,
    _Float16* __restrict__ h)
{
    int e = blockIdx.x * 2 + (threadIdx.x >> 7);
    int k = threadIdx.x & 127;
    if (e >= N_EDGES) return;
    const float* ea = edge_attr + (size_t)e * EDGE_DIM;
    const float* w  = W1 + (size_t)k * EDGE_DIM;
    float acc = b1[k];
#pragma unroll
    for (int d = 0; d < EDGE_DIM; ++d) acc += ea[d] * w[d];
    float g = 0.5f * acc * (1.0f + erff(acc * 0.70710678118654752f));
    h[(size_t)e * HID + k] = (_Float16)g;
}

// ---------------------------------------------------------------- phase 2
__global__ __launch_bounds__(256, 2) void edge_msg_mfma_kernel(
    const _Float16* __restrict__ hbuf,
    const float*    __restrict__ x,
    const int*      __restrict__ edge_index,   // [2][E] int32
    const _Float16* __restrict__ Wpk,
    const _Float16* __restrict__ b2pk,
    float* __restrict__ agg)                   // [N][64], pre-zeroed
{
    __shared__ float xsh[64 * 68];      // gathered x[src], pitch 68
    __shared__ float msgred[64 * 66];   // [i][e], pitch 66
    __shared__ int   dsts[64];

    const int e0   = blockIdx.x * 64;
    const int t    = threadIdx.x;
    const int wave = t >> 6;
    const int lane = t & 63;

    // ---- gather x[src[e]] rows into xsh (zero-fill invalid) + dsts
    {
        int le = t >> 2, sub = t & 3;
        int e = e0 + le;
        int s = -1;
        if (e < N_EDGES) {
            if (sub == 0) dsts[le] = edge_index[N_EDGES + e];
            s = edge_index[e];
        } else if (sub == 0) {
            dsts[le] = -1;
        }
#pragma unroll
        for (int q = 0; q < 4; ++q) {
            float4 v = make_float4(0.f, 0.f, 0.f, 0.f);
            if ((unsigned)s < (unsigned)N_NODES)
                v = ((const float4*)x)[(size_t)s * 16 + sub * 4 + q];
            *(float4*)&xsh[le * 68 + sub * 16 + q * 4] = v;
        }
    }

    // ---- per-wave resident h fragments (B operand), f16
    half8 hf[4][4];   // [nt][ks]
#pragma unroll
    for (int nt = 0; nt < 4; ++nt) {
#pragma unroll
        for (int ks = 0; ks < 4; ++ks) {
            int el = nt * 16 + (lane & 15);
            int ee = e0 + el; if (ee >= N_EDGES) ee = N_EDGES - 1;
            int gk = ks * 32 + ((lane >> 4) & 3) * 8;
            hf[nt][ks] = *(const half8*)(hbuf + (size_t)ee * HID + gk);
        }
    }
    __syncthreads();

    const f32x4 zero4 = {0.f, 0.f, 0.f, 0.f};
    f32x4 msg[4][4];  // [mt][nt]
#pragma unroll
    for (int mt = 0; mt < 4; ++mt)
#pragma unroll
        for (int nt = 0; nt < 4; ++nt) msg[mt][nt] = zero4;

    const half8* wpk8 = (const half8*)Wpk;

    // ---- main loop: this wave handles j = wave*16 .. wave*16+15
#pragma unroll 1
    for (int jj = 0; jj < 16; ++jj) {
        int j = wave * 16 + jj;
        float gv[4];
#pragma unroll
        for (int nt = 0; nt < 4; ++nt)
            gv[nt] = xsh[(nt * 16 + (lane & 15)) * 68 + j];

        size_t base = (size_t)j * 1024 + lane;
        f32x4 P[4][4];
#pragma unroll
        for (int ks = 0; ks < 4; ++ks) {
            half8 a[4];
#pragma unroll
            for (int mt = 0; mt < 4; ++mt) a[mt] = wpk8[base + ks * 256 + mt * 64];
#pragma unroll
            for (int mt = 0; mt < 4; ++mt)
#pragma unroll
                for (int nt = 0; nt < 4; ++nt)
                    P[mt][nt] = __builtin_amdgcn_mfma_f32_16x16x32_f16(
                        a[mt], hf[nt][ks], ks == 0 ? zero4 : P[mt][nt], 0, 0, 0);
        }
#pragma unroll
        for (int mt = 0; mt < 4; ++mt)
#pragma unroll
            for (int nt = 0; nt < 4; ++nt)
#pragma unroll
                for (int r = 0; r < 4; ++r)
                    msg[mt][nt][r] += gv[nt] * P[mt][nt][r];
    }

    // ---- bias term (wave 0 only): msg[i,e] += sum_j b2[i*64+j]*g[e,j]
    if (wave == 0) {
#pragma unroll
        for (int ks2 = 0; ks2 < 2; ++ks2) {
            half8 gf[4];
#pragma unroll
            for (int nt = 0; nt < 4; ++nt) {
                const float* gp = &xsh[(nt * 16 + (lane & 15)) * 68 + ks2 * 32 + ((lane >> 4) & 3) * 8];
                float4 lo = *(const float4*)gp;
                float4 hi = *(const float4*)(gp + 4);
                half8 g8;
                g8[0] = (_Float16)lo.x; g8[1] = (_Float16)lo.y;
                g8[2] = (_Float16)lo.z; g8[3] = (_Float16)lo.w;
                g8[4] = (_Float16)hi.x; g8[5] = (_Float16)hi.y;
                g8[6] = (_Float16)hi.z; g8[7] = (_Float16)hi.w;
                gf[nt] = g8;
            }
#pragma unroll
            for (int mt = 0; mt < 4; ++mt) {
                half8 bf8 = ((const half8*)b2pk)[ks2 * 256 + mt * 64 + lane];
#pragma unroll
                for (int nt = 0; nt < 4; ++nt)
                    msg[mt][nt] = __builtin_amdgcn_mfma_f32_16x16x32_f16(
                        bf8, gf[nt], msg[mt][nt], 0, 0, 0);
            }
        }
    }

    // ---- cross-wave reduce into msgred[i][e]
    if (wave == 0) {
#pragma unroll
        for (int mt = 0; mt < 4; ++mt)
#pragma unroll
            for (int nt = 0; nt < 4; ++nt)
#pragma unroll
                for (int r = 0; r < 4; ++r) {
                    int i = mt * 16 + ((lane >> 4) & 3) * 4 + r;
                    int e = nt * 16 + (lane & 15);
                    msgred[i * 66 + e] = msg[mt][nt][r];
                }
    }
    __syncthreads();
#pragma unroll 1
    for (int w = 1; w < 4; ++w) {
        if (wave == w) {
#pragma unroll
            for (int mt = 0; mt < 4; ++mt)
#pragma unroll
                for (int nt = 0; nt < 4; ++nt)
#pragma unroll
                    for (int r = 0; r < 4; ++r) {
                        int i = mt * 16 + ((lane >> 4) & 3) * 4 + r;
                        int e = nt * 16 + (lane & 15);
                        msgred[i * 66 + e] += msg[mt][nt][r];
                    }
        }
        __syncthreads();
    }

    // ---- scatter: agg[dst[e]][i] += msgred[i][e]
    {
        int e = t & 63;
        int iq = t >> 6;   // 0..3
        int d = dsts[e];
        if (e0 + e < N_EDGES && (unsigned)d < (unsigned)N_NODES) {
            float* dstp = agg + (size_t)d * NODE_DIM;
#pragma unroll
            for (int r = 0; r < 16; ++r) {
                int i = iq * 16 + r;
                atomicAdd(dstp + i, msgred[i * 66 + e]);
            }
        }
    }
}

// ---------------------------------------------------------------- phase 3
// GRUCell: 16 nodes per 1024-thread block; wave w owns node, lane t owns dim t
__global__ __launch_bounds__(1024) void gru_kernel(
    const float* __restrict__ agg,
    const float* __restrict__ x,
    const float* __restrict__ w_ih,
    const float* __restrict__ w_hh,
    const float* __restrict__ b_ih,
    const float* __restrict__ b_hh,
    float* __restrict__ out)
{
    int w = threadIdx.x >> 6;
    int t = threadIdx.x & 63;
    int n = blockIdx.x * 16 + w;
    __shared__ float as_[16][64], xs_[16][64];
    bool valid = n < N_NODES;
    if (valid) {
        as_[w][t] = agg[(size_t)n * NODE_DIM + t];
        xs_[w][t] = x[(size_t)n * NODE_DIM + t];
    }
    __syncthreads();
    if (!valid) return;

    float ir = b_ih[t], iz = b_ih[64 + t], inn = b_ih[128 + t];
    float hr = b_hh[t], hz = b_hh[64 + t], hn  = b_hh[128 + t];
    const float4* wi0 = reinterpret_cast<const float4*>(w_ih + (size_t)(t)       * 64);
    const float4* wi1 = reinterpret_cast<const float4*>(w_ih + (size_t)(64 + t)  * 64);
    const float4* wi2 = reinterpret_cast<const float4*>(w_ih + (size_t)(128 + t) * 64);
    const float4* wh0 = reinterpret_cast<const float4*>(w_hh + (size_t)(t)       * 64);
    const float4* wh1 = reinterpret_cast<const float4*>(w_hh + (size_t)(64 + t)  * 64);
    const float4* wh2 = reinterpret_cast<const float4*>(w_hh + (size_t)(128 + t) * 64);

#pragma unroll
    for (int kq = 0; kq < 16; ++kq) {
        float4 a4 = *reinterpret_cast<const float4*>(&as_[w][kq * 4]);
        float4 x4 = *reinterpret_cast<const float4*>(&xs_[w][kq * 4]);
        float4 wv;
        wv = wi0[kq]; ir  += a4.x * wv.x + a4.y * wv.y + a4.z * wv.z + a4.w * wv.w;
        wv = wi1[kq]; iz  += a4.x * wv.x + a4.y * wv.y + a4.z * wv.z + a4.w * wv.w;
        wv = wi2[kq]; inn += a4.x * wv.x + a4.y * wv.y + a4.z * wv.z + a4.w * wv.w;
        wv = wh0[kq]; hr  += x4.x * wv.x + x4.y * wv.y + x4.z * wv.z + x4.w * wv.w;
        wv = wh1[kq]; hz  += x4.x * wv.x + x4.y * wv.y + x4.z * wv.z + x4.w * wv.w;
        wv = wh2[kq]; hn  += x4.x * wv.x + x4.y * wv.y + x4.z * wv.z + x4.w * wv.w;
    }
    float r  = 1.f / (1.f + expf(-(ir + hr)));
    float z  = 1.f / (1.f + expf(-(iz + hz)));
    float nn = tanhf(inn + r * hn);
    out[(size_t)n * NODE_DIM + t] = (1.f - z) * nn + z * xs_[w][t];
}

// ---------------------------------------------------------------- launch
extern "C" void kernel_launch(void* const* d_in, const int* in_sizes, int n_in,
                              void* d_out, int out_size, void* d_ws, size_t ws_size,
                              hipStream_t stream)
{
    const float* x          = (const float*)d_in[0];
    const int*   edge_index = (const int*)  d_in[1];
    const float* edge_attr  = (const float*)d_in[2];
    const float* W1         = (const float*)d_in[3];
    const float* b1         = (const float*)d_in[4];
    const float* W2         = (const float*)d_in[5];
    const float* b2         = (const float*)d_in[6];
    const float* w_ih       = (const float*)d_in[7];
    const float* w_hh       = (const float*)d_in[8];
    const float* b_ih       = (const float*)d_in[9];
    const float* b_hh       = (const float*)d_in[10];
    float* out = (float*)d_out;

    char* ws = (char*)d_ws;
    _Float16* hbuf = (_Float16*)ws;                         // E*128 f16 = 12.8 MB
    ws += (size_t)N_EDGES * HID * sizeof(_Float16);
    _Float16* Wpk  = (_Float16*)ws;                         // 65536*8 f16 = 1 MB
    ws += (size_t)65536 * 8 * sizeof(_Float16);
    _Float16* b2pk = (_Float16*)ws;                         // 512*8 f16 = 8 KB
    ws += (size_t)512 * 8 * sizeof(_Float16);
    float* agg = (float*)ws;                                // N*64 f32 = 6.4 MB

    hipMemsetAsync(agg, 0, (size_t)N_NODES * NODE_DIM * sizeof(float), stream);

    prepack_kernel<<<dim3(258), dim3(256), 0, stream>>>(W2, b2, Wpk, b2pk);

    edge_mlp1_kernel<<<dim3(N_EDGES / 2), dim3(256), 0, stream>>>(edge_attr, W1, b1, hbuf);

    edge_msg_mfma_kernel<<<dim3((N_EDGES + 63) / 64), dim3(256), 0, stream>>>(
        hbuf, x, edge_index, Wpk, b2pk, agg);

    gru_kernel<<<dim3((N_NODES + 15) / 16), dim3(1024), 0, stream>>>(
        agg, x, w_ih, w_hh, b_ih, b_hh, out);
}

// Round 3
// 326.970 us; speedup vs baseline: 6.5480x; 2.7092x over previous
//
#include <hip/hip_runtime.h>
#include <math.h>

// EdgeConditionedConv on MI355X — round 2: fix GRU register-spill disaster.
// GRU now uses transposed weights (coalesced, L2-hot) + 8-node batching per
// wave. edge_msg MFMA kernel unchanged from round 1.

constexpr int N_NODES  = 25000;
constexpr int N_EDGES  = 50000;
constexpr int NODE_DIM = 64;
constexpr int EDGE_DIM = 16;
constexpr int HID      = 128;

typedef __attribute__((ext_vector_type(8))) _Float16 half8;
typedef __attribute__((ext_vector_type(4))) float    f32x4;

// ---------------------------------------------------------------- prepack
// Wpk chunk c = ((j*4+ks)*4+mt)*64+lane : 8 f16 = W2[(mt*16+(lane&15))*64+j][ks*32+((lane>>4)&3)*8 + 0..7]
// b2pk chunk c2 = (ks2*4+mt)*64+lane    : 8 f16 = b2[...]
// wT[k*192+g] = w[g*64+k] for w_ih -> wTih, w_hh -> wThh (fp32)
__global__ __launch_bounds__(256) void prepack_kernel(
    const float* __restrict__ W2, const float* __restrict__ b2,
    const float* __restrict__ w_ih, const float* __restrict__ w_hh,
    _Float16* __restrict__ Wpk, _Float16* __restrict__ b2pk,
    float* __restrict__ wTih, float* __restrict__ wThh)
{
    int c = blockIdx.x * 256 + threadIdx.x;
    if (c < 65536) {
        int lane = c & 63, mt = (c >> 6) & 3, ks = (c >> 8) & 3, j = c >> 10;
        int i   = mt * 16 + (lane & 15);
        int col = ks * 32 + ((lane >> 4) & 3) * 8;
        const float* src = W2 + (size_t)(i * 64 + j) * HID + col;
        half8 o;
#pragma unroll
        for (int q = 0; q < 8; ++q) o[q] = (_Float16)src[q];
        ((half8*)Wpk)[c] = o;
    } else if (c < 65536 + 512) {
        int c2 = c - 65536;
        int lane = c2 & 63, mt = (c2 >> 6) & 3, ks2 = (c2 >> 8) & 1;
        int i = mt * 16 + (lane & 15);
        int j = ks2 * 32 + ((lane >> 4) & 3) * 8;
        const float* src = b2 + i * 64 + j;
        half8 o;
#pragma unroll
        for (int q = 0; q < 8; ++q) o[q] = (_Float16)src[q];
        ((half8*)b2pk)[c2] = o;
    } else if (c < 65536 + 512 + 2 * 12288) {
        int idx = c - (65536 + 512);
        const float* src = (idx < 12288) ? w_ih : w_hh;
        float*       dst = (idx < 12288) ? wTih : wThh;
        int e2 = (idx < 12288) ? idx : idx - 12288;
        int k = e2 / 192, g = e2 - k * 192;
        dst[k * 192 + g] = src[(size_t)g * 64 + k];
    }
}

// ---------------------------------------------------------------- phase 1
__global__ __launch_bounds__(256) void edge_mlp1_kernel(
    const float* __restrict__ edge_attr,
    const float* __restrict__ W1,
    const float* __restrict__ b1,
    _Float16* __restrict__ h)
{
    int e = blockIdx.x * 2 + (threadIdx.x >> 7);
    int k = threadIdx.x & 127;
    if (e >= N_EDGES) return;
    const float* ea = edge_attr + (size_t)e * EDGE_DIM;
    const float* w  = W1 + (size_t)k * EDGE_DIM;
    float acc = b1[k];
#pragma unroll
    for (int d = 0; d < EDGE_DIM; ++d) acc += ea[d] * w[d];
    float g = 0.5f * acc * (1.0f + erff(acc * 0.70710678118654752f));
    h[(size_t)e * HID + k] = (_Float16)g;
}

// ---------------------------------------------------------------- phase 2
__global__ __launch_bounds__(256, 2) void edge_msg_mfma_kernel(
    const _Float16* __restrict__ hbuf,
    const float*    __restrict__ x,
    const int*      __restrict__ edge_index,   // [2][E] int32
    const _Float16* __restrict__ Wpk,
    const _Float16* __restrict__ b2pk,
    float* __restrict__ agg)                   // [N][64], pre-zeroed
{
    __shared__ float xsh[64 * 68];      // gathered x[src], pitch 68
    __shared__ float msgred[64 * 66];   // [i][e], pitch 66
    __shared__ int   dsts[64];

    const int e0   = blockIdx.x * 64;
    const int t    = threadIdx.x;
    const int wave = t >> 6;
    const int lane = t & 63;

    // ---- gather x[src[e]] rows into xsh (zero-fill invalid) + dsts
    {
        int le = t >> 2, sub = t & 3;
        int e = e0 + le;
        int s = -1;
        if (e < N_EDGES) {
            if (sub == 0) dsts[le] = edge_index[N_EDGES + e];
            s = edge_index[e];
        } else if (sub == 0) {
            dsts[le] = -1;
        }
#pragma unroll
        for (int q = 0; q < 4; ++q) {
            float4 v = make_float4(0.f, 0.f, 0.f, 0.f);
            if ((unsigned)s < (unsigned)N_NODES)
                v = ((const float4*)x)[(size_t)s * 16 + sub * 4 + q];
            *(float4*)&xsh[le * 68 + sub * 16 + q * 4] = v;
        }
    }

    // ---- per-wave resident h fragments (B operand), f16
    half8 hf[4][4];   // [nt][ks]
#pragma unroll
    for (int nt = 0; nt < 4; ++nt) {
#pragma unroll
        for (int ks = 0; ks < 4; ++ks) {
            int el = nt * 16 + (lane & 15);
            int ee = e0 + el; if (ee >= N_EDGES) ee = N_EDGES - 1;
            int gk = ks * 32 + ((lane >> 4) & 3) * 8;
            hf[nt][ks] = *(const half8*)(hbuf + (size_t)ee * HID + gk);
        }
    }
    __syncthreads();

    const f32x4 zero4 = {0.f, 0.f, 0.f, 0.f};
    f32x4 msg[4][4];  // [mt][nt]
#pragma unroll
    for (int mt = 0; mt < 4; ++mt)
#pragma unroll
        for (int nt = 0; nt < 4; ++nt) msg[mt][nt] = zero4;

    const half8* wpk8 = (const half8*)Wpk;

    // ---- main loop: this wave handles j = wave*16 .. wave*16+15
#pragma unroll 1
    for (int jj = 0; jj < 16; ++jj) {
        int j = wave * 16 + jj;
        float gv[4];
#pragma unroll
        for (int nt = 0; nt < 4; ++nt)
            gv[nt] = xsh[(nt * 16 + (lane & 15)) * 68 + j];

        size_t base = (size_t)j * 1024 + lane;
        f32x4 P[4][4];
#pragma unroll
        for (int ks = 0; ks < 4; ++ks) {
            half8 a[4];
#pragma unroll
            for (int mt = 0; mt < 4; ++mt) a[mt] = wpk8[base + ks * 256 + mt * 64];
#pragma unroll
            for (int mt = 0; mt < 4; ++mt)
#pragma unroll
                for (int nt = 0; nt < 4; ++nt)
                    P[mt][nt] = __builtin_amdgcn_mfma_f32_16x16x32_f16(
                        a[mt], hf[nt][ks], ks == 0 ? zero4 : P[mt][nt], 0, 0, 0);
        }
#pragma unroll
        for (int mt = 0; mt < 4; ++mt)
#pragma unroll
            for (int nt = 0; nt < 4; ++nt)
#pragma unroll
                for (int r = 0; r < 4; ++r)
                    msg[mt][nt][r] += gv[nt] * P[mt][nt][r];
    }

    // ---- bias term (wave 0 only): msg[i,e] += sum_j b2[i*64+j]*g[e,j]
    if (wave == 0) {
#pragma unroll
        for (int ks2 = 0; ks2 < 2; ++ks2) {
            half8 gf[4];
#pragma unroll
            for (int nt = 0; nt < 4; ++nt) {
                const float* gp = &xsh[(nt * 16 + (lane & 15)) * 68 + ks2 * 32 + ((lane >> 4) & 3) * 8];
                float4 lo = *(const float4*)gp;
                float4 hi = *(const float4*)(gp + 4);
                half8 g8;
                g8[0] = (_Float16)lo.x; g8[1] = (_Float16)lo.y;
                g8[2] = (_Float16)lo.z; g8[3] = (_Float16)lo.w;
                g8[4] = (_Float16)hi.x; g8[5] = (_Float16)hi.y;
                g8[6] = (_Float16)hi.z; g8[7] = (_Float16)hi.w;
                gf[nt] = g8;
            }
#pragma unroll
            for (int mt = 0; mt < 4; ++mt) {
                half8 bf8 = ((const half8*)b2pk)[ks2 * 256 + mt * 64 + lane];
#pragma unroll
                for (int nt = 0; nt < 4; ++nt)
                    msg[mt][nt] = __builtin_amdgcn_mfma_f32_16x16x32_f16(
                        bf8, gf[nt], msg[mt][nt], 0, 0, 0);
            }
        }
    }

    // ---- cross-wave reduce into msgred[i][e]
    if (wave == 0) {
#pragma unroll
        for (int mt = 0; mt < 4; ++mt)
#pragma unroll
            for (int nt = 0; nt < 4; ++nt)
#pragma unroll
                for (int r = 0; r < 4; ++r) {
                    int i = mt * 16 + ((lane >> 4) & 3) * 4 + r;
                    int e = nt * 16 + (lane & 15);
                    msgred[i * 66 + e] = msg[mt][nt][r];
                }
    }
    __syncthreads();
#pragma unroll 1
    for (int w = 1; w < 4; ++w) {
        if (wave == w) {
#pragma unroll
            for (int mt = 0; mt < 4; ++mt)
#pragma unroll
                for (int nt = 0; nt < 4; ++nt)
#pragma unroll
                    for (int r = 0; r < 4; ++r) {
                        int i = mt * 16 + ((lane >> 4) & 3) * 4 + r;
                        int e = nt * 16 + (lane & 15);
                        msgred[i * 66 + e] += msg[mt][nt][r];
                    }
        }
        __syncthreads();
    }

    // ---- scatter: agg[dst[e]][i] += msgred[i][e]
    {
        int e = t & 63;
        int iq = t >> 6;   // 0..3
        int d = dsts[e];
        if (e0 + e < N_EDGES && (unsigned)d < (unsigned)N_NODES) {
            float* dstp = agg + (size_t)d * NODE_DIM;
#pragma unroll
            for (int r = 0; r < 16; ++r) {
                int i = iq * 16 + r;
                atomicAdd(dstp + i, msgred[i * 66 + e]);
            }
        }
    }
}

// ---------------------------------------------------------------- phase 3
// GRUCell: 256 threads = 4 waves; each wave batches 8 nodes; lane t owns gate
// dims {t, 64+t, 128+t}. Weights transposed -> coalesced dword loads, L2-hot.
__global__ __launch_bounds__(256) void gru_kernel(
    const float* __restrict__ agg,
    const float* __restrict__ x,
    const float* __restrict__ wTih,   // [64][192]
    const float* __restrict__ wThh,   // [64][192]
    const float* __restrict__ b_ih,
    const float* __restrict__ b_hh,
    float* __restrict__ out)
{
    __shared__ float as_[32][64], xs_[32][64];
    const int t    = threadIdx.x;
    const int wave = t >> 6, lane = t & 63;
    const int n0   = blockIdx.x * 32;

    // stage 32 nodes of agg / x (coalesced float4)
    {
        const float4* asrc = (const float4*)(agg + (size_t)n0 * 64);
        const float4* xsrc = (const float4*)(x   + (size_t)n0 * 64);
        float4* ad = (float4*)&as_[0][0];
        float4* xd = (float4*)&xs_[0][0];
        int nvalid4 = min(N_NODES - n0, 32) * 16;
#pragma unroll
        for (int r = 0; r < 2; ++r) {
            int idx = t + r * 256;
            float4 v = make_float4(0.f, 0.f, 0.f, 0.f), u = v;
            if (idx < nvalid4) { v = asrc[idx]; u = xsrc[idx]; }
            ad[idx] = v; xd[idx] = u;
        }
    }
    __syncthreads();

    float accI0[8] = {}, accI1[8] = {}, accI2[8] = {};
    float accH0[8] = {}, accH1[8] = {}, accH2[8] = {};

#pragma unroll 4
    for (int k = 0; k < 64; ++k) {
        float wi0 = wTih[k * 192 + lane];
        float wi1 = wTih[k * 192 + 64 + lane];
        float wi2 = wTih[k * 192 + 128 + lane];
        float wh0 = wThh[k * 192 + lane];
        float wh1 = wThh[k * 192 + 64 + lane];
        float wh2 = wThh[k * 192 + 128 + lane];
#pragma unroll
        for (int n = 0; n < 8; ++n) {
            float a  = as_[wave * 8 + n][k];
            float xx = xs_[wave * 8 + n][k];
            accI0[n] += a * wi0;  accI1[n] += a * wi1;  accI2[n] += a * wi2;
            accH0[n] += xx * wh0; accH1[n] += xx * wh1; accH2[n] += xx * wh2;
        }
    }

    float bi0 = b_ih[lane], bi1 = b_ih[64 + lane], bi2 = b_ih[128 + lane];
    float bh0 = b_hh[lane], bh1 = b_hh[64 + lane], bh2 = b_hh[128 + lane];
#pragma unroll
    for (int n = 0; n < 8; ++n) {
        int node = n0 + wave * 8 + n;
        if (node >= N_NODES) break;
        float r  = 1.f / (1.f + expf(-(accI0[n] + bi0 + accH0[n] + bh0)));
        float z  = 1.f / (1.f + expf(-(accI1[n] + bi1 + accH1[n] + bh1)));
        float nn = tanhf(accI2[n] + bi2 + r * (accH2[n] + bh2));
        out[(size_t)node * 64 + lane] = (1.f - z) * nn + z * xs_[wave * 8 + n][lane];
    }
}

// ---------------------------------------------------------------- launch
extern "C" void kernel_launch(void* const* d_in, const int* in_sizes, int n_in,
                              void* d_out, int out_size, void* d_ws, size_t ws_size,
                              hipStream_t stream)
{
    const float* x          = (const float*)d_in[0];
    const int*   edge_index = (const int*)  d_in[1];
    const float* edge_attr  = (const float*)d_in[2];
    const float* W1         = (const float*)d_in[3];
    const float* b1         = (const float*)d_in[4];
    const float* W2         = (const float*)d_in[5];
    const float* b2         = (const float*)d_in[6];
    const float* w_ih       = (const float*)d_in[7];
    const float* w_hh       = (const float*)d_in[8];
    const float* b_ih       = (const float*)d_in[9];
    const float* b_hh       = (const float*)d_in[10];
    float* out = (float*)d_out;

    char* ws = (char*)d_ws;
    _Float16* hbuf = (_Float16*)ws;                         // E*128 f16 = 12.8 MB
    ws += (size_t)N_EDGES * HID * sizeof(_Float16);
    _Float16* Wpk  = (_Float16*)ws;                         // 1 MB
    ws += (size_t)65536 * 8 * sizeof(_Float16);
    _Float16* b2pk = (_Float16*)ws;                         // 8 KB
    ws += (size_t)512 * 8 * sizeof(_Float16);
    float* wTih = (float*)ws;                               // 48 KB
    ws += (size_t)64 * 192 * sizeof(float);
    float* wThh = (float*)ws;                               // 48 KB
    ws += (size_t)64 * 192 * sizeof(float);
    float* agg = (float*)ws;                                // N*64 f32 = 6.4 MB

    hipMemsetAsync(agg, 0, (size_t)N_NODES * NODE_DIM * sizeof(float), stream);

    prepack_kernel<<<dim3(355), dim3(256), 0, stream>>>(
        W2, b2, w_ih, w_hh, Wpk, b2pk, wTih, wThh);

    edge_mlp1_kernel<<<dim3(N_EDGES / 2), dim3(256), 0, stream>>>(edge_attr, W1, b1, hbuf);

    edge_msg_mfma_kernel<<<dim3((N_EDGES + 63) / 64), dim3(256), 0, stream>>>(
        hbuf, x, edge_index, Wpk, b2pk, agg);

    gru_kernel<<<dim3((N_NODES + 31) / 32), dim3(256), 0, stream>>>(
        agg, x, wTih, wThh, b_ih, b_hh, out);
}

// Round 4
// 180.186 us; speedup vs baseline: 11.8821x; 1.8146x over previous
//
#include <hip/hip_runtime.h>
#include <math.h>

// EdgeConditionedConv on MI355X — round 3: coalesced atomic scatter.
// Round-2 postmortem: 3.2M scattered 4B atomics (64 lanes -> 64 node rows)
// caused 100 MB HBM write traffic and serialized the kernel. Now one atomic
// instruction covers one edge row (lane = output dim) -> 4 cachelines.

constexpr int N_NODES  = 25000;
constexpr int N_EDGES  = 50000;
constexpr int NODE_DIM = 64;
constexpr int EDGE_DIM = 16;
constexpr int HID      = 128;

typedef __attribute__((ext_vector_type(8))) _Float16 half8;
typedef __attribute__((ext_vector_type(4))) float    f32x4;

// ---------------------------------------------------------------- prepack
__global__ __launch_bounds__(256) void prepack_kernel(
    const float* __restrict__ W2, const float* __restrict__ b2,
    const float* __restrict__ w_ih, const float* __restrict__ w_hh,
    _Float16* __restrict__ Wpk, _Float16* __restrict__ b2pk,
    float* __restrict__ wTih, float* __restrict__ wThh)
{
    int c = blockIdx.x * 256 + threadIdx.x;
    if (c < 65536) {
        int lane = c & 63, mt = (c >> 6) & 3, ks = (c >> 8) & 3, j = c >> 10;
        int i   = mt * 16 + (lane & 15);
        int col = ks * 32 + ((lane >> 4) & 3) * 8;
        const float* src = W2 + (size_t)(i * 64 + j) * HID + col;
        half8 o;
#pragma unroll
        for (int q = 0; q < 8; ++q) o[q] = (_Float16)src[q];
        ((half8*)Wpk)[c] = o;
    } else if (c < 65536 + 512) {
        int c2 = c - 65536;
        int lane = c2 & 63, mt = (c2 >> 6) & 3, ks2 = (c2 >> 8) & 1;
        int i = mt * 16 + (lane & 15);
        int j = ks2 * 32 + ((lane >> 4) & 3) * 8;
        const float* src = b2 + i * 64 + j;
        half8 o;
#pragma unroll
        for (int q = 0; q < 8; ++q) o[q] = (_Float16)src[q];
        ((half8*)b2pk)[c2] = o;
    } else if (c < 65536 + 512 + 2 * 12288) {
        int idx = c - (65536 + 512);
        const float* src = (idx < 12288) ? w_ih : w_hh;
        float*       dst = (idx < 12288) ? wTih : wThh;
        int e2 = (idx < 12288) ? idx : idx - 12288;
        int k = e2 / 192, g = e2 - k * 192;
        dst[k * 192 + g] = src[(size_t)g * 64 + k];
    }
}

// ---------------------------------------------------------------- phase 1
__global__ __launch_bounds__(256) void edge_mlp1_kernel(
    const float* __restrict__ edge_attr,
    const float* __restrict__ W1,
    const float* __restrict__ b1,
    _Float16* __restrict__ h)
{
    int e = blockIdx.x * 2 + (threadIdx.x >> 7);
    int k = threadIdx.x & 127;
    if (e >= N_EDGES) return;
    const float* ea = edge_attr + (size_t)e * EDGE_DIM;
    const float* w  = W1 + (size_t)k * EDGE_DIM;
    float acc = b1[k];
#pragma unroll
    for (int d = 0; d < EDGE_DIM; ++d) acc += ea[d] * w[d];
    float g = 0.5f * acc * (1.0f + erff(acc * 0.70710678118654752f));
    h[(size_t)e * HID + k] = (_Float16)g;
}

// ---------------------------------------------------------------- phase 2
__global__ __launch_bounds__(256, 2) void edge_msg_mfma_kernel(
    const _Float16* __restrict__ hbuf,
    const float*    __restrict__ x,
    const int*      __restrict__ edge_index,   // [2][E] int32
    const _Float16* __restrict__ Wpk,
    const _Float16* __restrict__ b2pk,
    float* __restrict__ agg)                   // [N][64], pre-zeroed
{
    __shared__ float xsh[64 * 68];      // gathered x[src], pitch 68
    __shared__ float msgred[64 * 67];   // [i][e], pitch 67
    __shared__ int   dsts[64];

    const int e0   = blockIdx.x * 64;
    const int t    = threadIdx.x;
    const int wave = t >> 6;
    const int lane = t & 63;

    // ---- gather x[src[e]] rows into xsh (zero-fill invalid) + dsts
    {
        int le = t >> 2, sub = t & 3;
        int e = e0 + le;
        int s = -1;
        if (e < N_EDGES) {
            if (sub == 0) dsts[le] = edge_index[N_EDGES + e];
            s = edge_index[e];
        } else if (sub == 0) {
            dsts[le] = -1;
        }
#pragma unroll
        for (int q = 0; q < 4; ++q) {
            float4 v = make_float4(0.f, 0.f, 0.f, 0.f);
            if ((unsigned)s < (unsigned)N_NODES)
                v = ((const float4*)x)[(size_t)s * 16 + sub * 4 + q];
            *(float4*)&xsh[le * 68 + sub * 16 + q * 4] = v;
        }
    }

    // ---- per-wave resident h fragments (B operand), f16
    half8 hf[4][4];   // [nt][ks]
#pragma unroll
    for (int nt = 0; nt < 4; ++nt) {
#pragma unroll
        for (int ks = 0; ks < 4; ++ks) {
            int el = nt * 16 + (lane & 15);
            int ee = e0 + el; if (ee >= N_EDGES) ee = N_EDGES - 1;
            int gk = ks * 32 + ((lane >> 4) & 3) * 8;
            hf[nt][ks] = *(const half8*)(hbuf + (size_t)ee * HID + gk);
        }
    }
    __syncthreads();

    const f32x4 zero4 = {0.f, 0.f, 0.f, 0.f};
    f32x4 msg[4][4];  // [mt][nt]
#pragma unroll
    for (int mt = 0; mt < 4; ++mt)
#pragma unroll
        for (int nt = 0; nt < 4; ++nt) msg[mt][nt] = zero4;

    const half8* wpk8 = (const half8*)Wpk;

    // ---- main loop: this wave handles j = wave*16 .. wave*16+15
#pragma unroll 1
    for (int jj = 0; jj < 16; ++jj) {
        int j = wave * 16 + jj;
        float gv[4];
#pragma unroll
        for (int nt = 0; nt < 4; ++nt)
            gv[nt] = xsh[(nt * 16 + (lane & 15)) * 68 + j];

        size_t base = (size_t)j * 1024 + lane;
        half8 a[4][4];   // [ks][mt] — issue all 16 loads upfront
#pragma unroll
        for (int ks = 0; ks < 4; ++ks)
#pragma unroll
            for (int mt = 0; mt < 4; ++mt)
                a[ks][mt] = wpk8[base + ks * 256 + mt * 64];

        f32x4 P[4][4];
#pragma unroll
        for (int ks = 0; ks < 4; ++ks)
#pragma unroll
            for (int mt = 0; mt < 4; ++mt)
#pragma unroll
                for (int nt = 0; nt < 4; ++nt)
                    P[mt][nt] = __builtin_amdgcn_mfma_f32_16x16x32_f16(
                        a[ks][mt], hf[nt][ks], ks == 0 ? zero4 : P[mt][nt], 0, 0, 0);
#pragma unroll
        for (int mt = 0; mt < 4; ++mt)
#pragma unroll
            for (int nt = 0; nt < 4; ++nt)
#pragma unroll
                for (int r = 0; r < 4; ++r)
                    msg[mt][nt][r] += gv[nt] * P[mt][nt][r];
    }

    // ---- bias term (wave 0 only): msg[i,e] += sum_j b2[i*64+j]*g[e,j]
    if (wave == 0) {
#pragma unroll
        for (int ks2 = 0; ks2 < 2; ++ks2) {
            half8 gf[4];
#pragma unroll
            for (int nt = 0; nt < 4; ++nt) {
                const float* gp = &xsh[(nt * 16 + (lane & 15)) * 68 + ks2 * 32 + ((lane >> 4) & 3) * 8];
                float4 lo = *(const float4*)gp;
                float4 hi = *(const float4*)(gp + 4);
                half8 g8;
                g8[0] = (_Float16)lo.x; g8[1] = (_Float16)lo.y;
                g8[2] = (_Float16)lo.z; g8[3] = (_Float16)lo.w;
                g8[4] = (_Float16)hi.x; g8[5] = (_Float16)hi.y;
                g8[6] = (_Float16)hi.z; g8[7] = (_Float16)hi.w;
                gf[nt] = g8;
            }
#pragma unroll
            for (int mt = 0; mt < 4; ++mt) {
                half8 bf8 = ((const half8*)b2pk)[ks2 * 256 + mt * 64 + lane];
#pragma unroll
                for (int nt = 0; nt < 4; ++nt)
                    msg[mt][nt] = __builtin_amdgcn_mfma_f32_16x16x32_f16(
                        bf8, gf[nt], msg[mt][nt], 0, 0, 0);
            }
        }
    }

    // ---- cross-wave reduce into msgred[i][e]
    if (wave == 0) {
#pragma unroll
        for (int mt = 0; mt < 4; ++mt)
#pragma unroll
            for (int nt = 0; nt < 4; ++nt)
#pragma unroll
                for (int r = 0; r < 4; ++r) {
                    int i = mt * 16 + ((lane >> 4) & 3) * 4 + r;
                    int e = nt * 16 + (lane & 15);
                    msgred[i * 67 + e] = msg[mt][nt][r];
                }
    }
    __syncthreads();
#pragma unroll 1
    for (int w = 1; w < 4; ++w) {
        if (wave == w) {
#pragma unroll
            for (int mt = 0; mt < 4; ++mt)
#pragma unroll
                for (int nt = 0; nt < 4; ++nt)
#pragma unroll
                    for (int r = 0; r < 4; ++r) {
                        int i = mt * 16 + ((lane >> 4) & 3) * 4 + r;
                        int e = nt * 16 + (lane & 15);
                        msgred[i * 67 + e] += msg[mt][nt][r];
                    }
        }
        __syncthreads();
    }

    // ---- scatter, COALESCED: one edge row per atomic instr (lane = dim i)
    {
#pragma unroll 1
        for (int ee = wave; ee < 64; ee += 4) {
            int d = dsts[ee];
            if (e0 + ee < N_EDGES && (unsigned)d < (unsigned)N_NODES)
                atomicAdd(agg + (size_t)d * NODE_DIM + lane, msgred[lane * 67 + ee]);
        }
    }
}

// ---------------------------------------------------------------- phase 3
// GRUCell: 4 waves x 8 nodes; lane t owns gate dims {t,64+t,128+t};
// transposed weights -> coalesced, L2-hot.
__global__ __launch_bounds__(256) void gru_kernel(
    const float* __restrict__ agg,
    const float* __restrict__ x,
    const float* __restrict__ wTih,   // [64][192]
    const float* __restrict__ wThh,   // [64][192]
    const float* __restrict__ b_ih,
    const float* __restrict__ b_hh,
    float* __restrict__ out)
{
    __shared__ float as_[32][64], xs_[32][64];
    const int t    = threadIdx.x;
    const int wave = t >> 6, lane = t & 63;
    const int n0   = blockIdx.x * 32;

    {
        const float4* asrc = (const float4*)(agg + (size_t)n0 * 64);
        const float4* xsrc = (const float4*)(x   + (size_t)n0 * 64);
        float4* ad = (float4*)&as_[0][0];
        float4* xd = (float4*)&xs_[0][0];
        int nvalid4 = min(N_NODES - n0, 32) * 16;
#pragma unroll
        for (int r = 0; r < 2; ++r) {
            int idx = t + r * 256;
            float4 v = make_float4(0.f, 0.f, 0.f, 0.f), u = v;
            if (idx < nvalid4) { v = asrc[idx]; u = xsrc[idx]; }
            ad[idx] = v; xd[idx] = u;
        }
    }
    __syncthreads();

    float accI0[8] = {}, accI1[8] = {}, accI2[8] = {};
    float accH0[8] = {}, accH1[8] = {}, accH2[8] = {};

#pragma unroll 4
    for (int k = 0; k < 64; ++k) {
        float wi0 = wTih[k * 192 + lane];
        float wi1 = wTih[k * 192 + 64 + lane];
        float wi2 = wTih[k * 192 + 128 + lane];
        float wh0 = wThh[k * 192 + lane];
        float wh1 = wThh[k * 192 + 64 + lane];
        float wh2 = wThh[k * 192 + 128 + lane];
#pragma unroll
        for (int n = 0; n < 8; ++n) {
            float a  = as_[wave * 8 + n][k];
            float xx = xs_[wave * 8 + n][k];
            accI0[n] += a * wi0;  accI1[n] += a * wi1;  accI2[n] += a * wi2;
            accH0[n] += xx * wh0; accH1[n] += xx * wh1; accH2[n] += xx * wh2;
        }
    }

    float bi0 = b_ih[lane], bi1 = b_ih[64 + lane], bi2 = b_ih[128 + lane];
    float bh0 = b_hh[lane], bh1 = b_hh[64 + lane], bh2 = b_hh[128 + lane];
#pragma unroll
    for (int n = 0; n < 8; ++n) {
        int node = n0 + wave * 8 + n;
        if (node >= N_NODES) break;
        float r  = 1.f / (1.f + expf(-(accI0[n] + bi0 + accH0[n] + bh0)));
        float z  = 1.f / (1.f + expf(-(accI1[n] + bi1 + accH1[n] + bh1)));
        float nn = tanhf(accI2[n] + bi2 + r * (accH2[n] + bh2));
        out[(size_t)node * 64 + lane] = (1.f - z) * nn + z * xs_[wave * 8 + n][lane];
    }
}

// ---------------------------------------------------------------- launch
extern "C" void kernel_launch(void* const* d_in, const int* in_sizes, int n_in,
                              void* d_out, int out_size, void* d_ws, size_t ws_size,
                              hipStream_t stream)
{
    const float* x          = (const float*)d_in[0];
    const int*   edge_index = (const int*)  d_in[1];
    const float* edge_attr  = (const float*)d_in[2];
    const float* W1         = (const float*)d_in[3];
    const float* b1         = (const float*)d_in[4];
    const float* W2         = (const float*)d_in[5];
    const float* b2         = (const float*)d_in[6];
    const float* w_ih       = (const float*)d_in[7];
    const float* w_hh       = (const float*)d_in[8];
    const float* b_ih       = (const float*)d_in[9];
    const float* b_hh       = (const float*)d_in[10];
    float* out = (float*)d_out;

    char* ws = (char*)d_ws;
    _Float16* hbuf = (_Float16*)ws;                         // 12.8 MB
    ws += (size_t)N_EDGES * HID * sizeof(_Float16);
    _Float16* Wpk  = (_Float16*)ws;                         // 1 MB
    ws += (size_t)65536 * 8 * sizeof(_Float16);
    _Float16* b2pk = (_Float16*)ws;                         // 8 KB
    ws += (size_t)512 * 8 * sizeof(_Float16);
    float* wTih = (float*)ws;                               // 48 KB
    ws += (size_t)64 * 192 * sizeof(float);
    float* wThh = (float*)ws;                               // 48 KB
    ws += (size_t)64 * 192 * sizeof(float);
    float* agg = (float*)ws;                                // 6.4 MB

    hipMemsetAsync(agg, 0, (size_t)N_NODES * NODE_DIM * sizeof(float), stream);

    prepack_kernel<<<dim3(355), dim3(256), 0, stream>>>(
        W2, b2, w_ih, w_hh, Wpk, b2pk, wTih, wThh);

    edge_mlp1_kernel<<<dim3(N_EDGES / 2), dim3(256), 0, stream>>>(edge_attr, W1, b1, hbuf);

    edge_msg_mfma_kernel<<<dim3((N_EDGES + 63) / 64), dim3(256), 0, stream>>>(
        hbuf, x, edge_index, Wpk, b2pk, agg);

    gru_kernel<<<dim3((N_NODES + 31) / 32), dim3(256), 0, stream>>>(
        agg, x, wTih, wThh, b_ih, b_hh, out);
}